// Round 8
// baseline (307.869 us; speedup 1.0000x reference)
//
#include <hip/hip_runtime.h>

#define BB 32
#define TT 8
#define NN 1024
#define KNN 20
#define HH 64
#define CLS 14

__device__ __constant__ float kEPS = 1e-5f;

// order-preserving flip: float bits -> uint with same total order
__device__ __forceinline__ unsigned flipbits(unsigned u) {
    return u ^ ((unsigned)((int)u >> 31) | 0x80000000u);
}
// inverse of flipbits
__device__ __forceinline__ float unflip(unsigned fu) {
    const unsigned u = (fu & 0x80000000u) ? (fu ^ 0x80000000u) : ~fu;
    return __uint_as_float(u);
}
__device__ __forceinline__ int mbcnt64(unsigned long long m) {
    return (int)__builtin_amdgcn_mbcnt_hi((unsigned)(m >> 32),
            __builtin_amdgcn_mbcnt_lo((unsigned)m, 0u));
}

// Exact iterative extraction fallback (survivor-buffer overflow only; cold).
// Flips d[] to ordered-uint IN PLACE (no second array -> no extra VGPRs).
__device__ __forceinline__ void fallback20_f(float d[16], int lane, unsigned* nb) {
    #pragma unroll
    for (int i = 0; i < 16; ++i)
        d[i] = __uint_as_float(flipbits(__float_as_uint(d[i])));
    for (int kk = 0; kk < KNN; ++kk) {
        unsigned bv = __float_as_uint(d[0]);
        int bi = 0;
        #pragma unroll
        for (int i = 1; i < 16; ++i) {
            const unsigned v = __float_as_uint(d[i]);
            if (v < bv) { bv = v; bi = i; }
        }
        unsigned bj = (unsigned)(bi * 64 + lane);
        #pragma unroll
        for (int off = 32; off >= 1; off >>= 1) {
            const unsigned ov = __shfl_xor(bv, off, 64);
            const unsigned oj = __shfl_xor(bj, off, 64);
            if (ov < bv || (ov == bv && oj < bj)) { bv = ov; bj = oj; }
        }
        if (lane == 0) nb[kk] = bj;
        #pragma unroll
        for (int i = 0; i < 16; ++i)
            if (bj == (unsigned)(i * 64 + lane)) d[i] = __uint_as_float(0xFFFFFFFFu);
    }
}

// ---------------------------------------------------------------------------
// Kernel A: per (t, b, 64-point chunk). One wave = 16 query points, one at a
// time. Latency-bound on serial ballot chains -> occupancy is the lever; the
// 64-VGPR cliff rules (R4-R7). launch_bounds(256,4) pins VGPR=64; this round
// diets the register pressure so the clamp is (near-)spill-free:
//  - per-lane MLP constants live in LDS (cstA/cstB), re-read after selection
//  - fallback flips d[] in place (no second array)
//  - dist loop unroll capped at 4 (bounded LDS-staging temps)
// Selection per point: float distances -> per-lane min -> 12-step ballot
// radix -> UB >= d(20) -> ballot-compact survivors to LDS -> 32-step ballot
// radix = exact v20 -> exact jax top-20 set ({<v20} U lowest-index ties) ->
// EdgeConv with deferred ReLU/BN (zmax only); atomicMax epilogue.
// ---------------------------------------------------------------------------
__global__ __launch_bounds__(256, 4) void knn_edge_kernel(
    const float* __restrict__ x,    // [B,T,N,3]
    const float* __restrict__ W1,   // [6,H]
    const float* __restrict__ b1,   // [H]
    const float* __restrict__ g1,   // [H]
    const float* __restrict__ be1,  // [H]
    float* __restrict__ acc)        // [B, 7*H], zero-initialized
{
    __shared__ float4 pts[NN];                      // x, y, z, |p|^2
    __shared__ unsigned long long keybuf[4][64];    // per-wave survivor keys
    __shared__ unsigned nbuf[4][KNN];               // per-wave neighbor indices
    __shared__ unsigned smax[HH];
    __shared__ float4 cstA[HH];                     // w03, w14, w25, sgn
    __shared__ float4 cstB[HH];                     // w3,  w4,  w5,  b1l

    const int chunk = blockIdx.x;   // 0..15
    const int b     = blockIdx.y;   // 0..31
    const int t     = blockIdx.z;   // 0..6

    const int tid  = threadIdx.x;
    const int lane = tid & 63;
    const int wave = tid >> 6;

    for (int i = tid; i < NN; i += 256) {
        const float* p = x + (((size_t)b * TT + t) * NN + i) * 3;
        const float px = p[0], py = p[1], pz = p[2];
        pts[i] = make_float4(px, py, pz, px * px + py * py + pz * pz);
    }
    if (tid < HH) {
        smax[tid] = 0u;
        const float w0 = W1[0 * HH + tid], w1 = W1[1 * HH + tid],
                    w2 = W1[2 * HH + tid], w3 = W1[3 * HH + tid],
                    w4 = W1[4 * HH + tid], w5 = W1[5 * HH + tid];
        const float scale = g1[tid] / sqrtf(1.0f + kEPS);
        const float sgn = (scale >= 0.0f) ? 1.0f : -1.0f;
        cstA[tid] = make_float4(sgn * (w0 - w3), sgn * (w1 - w4), sgn * (w2 - w5), sgn);
        cstB[tid] = make_float4(w3, w4, w5, b1[tid]);
    }
    __syncthreads();

    float zmax = -3.0e38f;   // max over edges of sign-corrected pre-activation

    const int n0 = chunk * 64 + wave * 16;
    for (int p = 0; p < 16; ++p) {
        const int n = n0 + p;
        const float* c = x + (((size_t)b * TT + (t + 1)) * NN + n) * 3;
        const float cx = c[0], cy = c[1], cz = c[2];      // wave-uniform -> SGPR
        const float s1 = cx * cx + cy * cy + cz * cz;
        const float n2x = -2.0f * cx, n2y = -2.0f * cy, n2z = -2.0f * cz;

        // float distances + per-lane min (bounded staging)
        float d[16];
        float mnf = 3.0e38f;
        #pragma unroll 4
        for (int i = 0; i < 16; ++i) {
            const float4 q = pts[i * 64 + lane];
            d[i] = fmaf(n2x, q.x, fmaf(n2y, q.y, fmaf(n2z, q.z, s1 + q.w)));
            mnf = fminf(mnf, d[i]);
        }
        const unsigned mn = flipbits(__float_as_uint(mnf));

        // 12-step ballot radix on lane-mins: UB >= 20th lane-min >= d(20)
        unsigned pp = 0;
        int krem = 19;
        #pragma unroll
        for (int bit = 31; bit >= 20; --bit) {
            const unsigned long long z = __ballot(((mn ^ pp) >> bit) == 0u);
            const int c0 = (int)__popcll(z);
            if (krem >= c0) { pp |= (1u << bit); krem -= c0; }
        }
        const float ubf = unflip(pp | 0xFFFFFu);   // finite

        // ballot-compact survivors (d <= ubf) into per-wave LDS key buffer
        int base = 0;
        #pragma unroll
        for (int i = 0; i < 16; ++i) {
            const bool pr = d[i] <= ubf;
            const unsigned long long mk = __ballot(pr);
            if (pr) {
                const int pos = base + mbcnt64(mk);
                if (pos < 64) keybuf[wave][pos] =
                    ((unsigned long long)__float_as_uint(d[i]) << 32)
                    | (unsigned)(i * 64 + lane);
            }
            base += (int)__popcll(mk);
        }

        if (base <= 64) {
            const unsigned long long key = keybuf[wave][lane];
            const bool valid = lane < base;
            const unsigned sfd = valid ? flipbits((unsigned)(key >> 32)) : 0xFFFFFFFFu;
            const unsigned sidx = (unsigned)key & 1023u;

            // exact v20 (rank-19 survivor) via 32-step ballot radix-select
            unsigned v20 = 0;
            int k2 = 19;
            #pragma unroll
            for (int bit = 31; bit >= 0; --bit) {
                const unsigned long long z = __ballot(valid && ((sfd ^ v20) >> bit) == 0u);
                const int c0 = (int)__popcll(z);
                if (k2 >= c0) { v20 |= (1u << bit); k2 -= c0; }
            }

            // exact top-20 set: {fd < v20} U lowest-index ties at v20
            const unsigned long long ltm = __ballot(valid && sfd < v20);
            const int need = KNN - (int)__popcll(ltm);
            const unsigned long long tiedm = __ballot(valid && sfd == v20);
            bool sel;
            if ((int)__popcll(tiedm) == need) {
                sel = valid && sfd <= v20;
            } else {
                int r = 0;
                unsigned long long mm = tiedm;
                while (mm) {
                    const int l = __builtin_ctzll(mm);
                    const unsigned oi = __shfl(sidx, l, 64);
                    r += (oi < sidx) ? 1 : 0;
                    mm &= mm - 1;
                }
                sel = valid && (sfd < v20 || (sfd == v20 && r < need));
            }
            const unsigned long long sm = __ballot(sel);
            if (sel) nbuf[wave][mbcnt64(sm)] = sidx;
        } else {
            fallback20_f(d, lane, &nbuf[wave][0]);   // cold; in-place flip
        }

        // EdgeConv, lane = channel, relu/BN deferred. Constants from LDS
        // (loaded AFTER selection so they never overlap d[16]'s live range).
        const float4 ca = cstA[lane];   // w03, w14, w25, sgn
        const float4 cb = cstB[lane];   // w3,  w4,  w5,  b1l
        const float mb = ca.w * fmaf(cx, cb.x, fmaf(cy, cb.y, fmaf(cz, cb.z, cb.w)));
        #pragma unroll
        for (int kk = 0; kk < KNN; ++kk) {
            const int j = (int)nbuf[wave][kk];     // uniform -> LDS broadcast
            const float4 q = pts[j];
            const float z = fmaf(q.x, ca.x, fmaf(q.y, ca.y, fmaf(q.z, ca.z, mb)));
            zmax = fmaxf(zmax, z);
        }
    }

    // epilogue: re-read channel constants (cold), undo sign, relu, BN, clamp
    {
        const float scale = g1[lane] / sqrtf(1.0f + kEPS);
        const float sgn = (scale >= 0.0f) ? 1.0f : -1.0f;
        const float r  = fmaxf(sgn * zmax, 0.0f);
        const float h  = fmaf(r, scale, be1[lane]);
        const float cm = fmaxf(h, 0.0f);
        atomicMax(&smax[lane], __float_as_uint(cm));
    }
    __syncthreads();
    if (tid < HH) {
        unsigned* dst = (unsigned*)(acc + ((size_t)b * 448 + t * 64 + tid));
        atomicMax(dst, smax[tid]);
    }
}

// ---------------------------------------------------------------------------
// Kernel B: MLP head, one block (512 threads) per batch row.
// ---------------------------------------------------------------------------
__global__ __launch_bounds__(512) void head_kernel(
    const float* __restrict__ acc,  // [B,448]
    const float* __restrict__ Wa, const float* __restrict__ ba,
    const float* __restrict__ ga, const float* __restrict__ bea,
    const float* __restrict__ Wb, const float* __restrict__ bb,
    const float* __restrict__ gb, const float* __restrict__ beb,
    const float* __restrict__ Wc, const float* __restrict__ bc,
    float* __restrict__ out)        // [B,CLS]
{
    __shared__ float s0[448];
    __shared__ float h1[512];
    __shared__ float h2[256];
    __shared__ float lg[CLS];
    __shared__ float red[2];

    const int b   = blockIdx.x;
    const int tid = threadIdx.x;
    const float inv = 1.0f / sqrtf(1.0f + kEPS);

    if (tid < 448) s0[tid] = acc[(size_t)b * 448 + tid];
    __syncthreads();

    {   // layer a: 448 -> 512
        float s = ba[tid];
        for (int d = 0; d < 448; ++d) s = fmaf(s0[d], Wa[d * 512 + tid], s);
        s = fmaxf(s, 0.0f);
        h1[tid] = fmaf(s, ga[tid] * inv, bea[tid]);
    }
    __syncthreads();
    if (tid < 256) {  // layer b: 512 -> 256
        float s = bb[tid];
        for (int d = 0; d < 512; ++d) s = fmaf(h1[d], Wb[d * 256 + tid], s);
        s = fmaxf(s, 0.0f);
        h2[tid] = fmaf(s, gb[tid] * inv, beb[tid]);
    }
    __syncthreads();
    if (tid < CLS) {  // logits: 256 -> 14
        float s = bc[tid];
        for (int d = 0; d < 256; ++d) s = fmaf(h2[d], Wc[d * CLS + tid], s);
        lg[tid] = s;
    }
    __syncthreads();
    if (tid == 0) {   // log_softmax over 14 classes
        float m = lg[0];
        for (int j = 1; j < CLS; ++j) m = fmaxf(m, lg[j]);
        float ssum = 0.0f;
        for (int j = 0; j < CLS; ++j) ssum += expf(lg[j] - m);
        red[0] = m;
        red[1] = logf(ssum);
    }
    __syncthreads();
    if (tid < CLS) out[(size_t)b * CLS + tid] = lg[tid] - red[0] - red[1];
}

extern "C" void kernel_launch(void* const* d_in, const int* in_sizes, int n_in,
                              void* d_out, int out_size, void* d_ws, size_t ws_size,
                              hipStream_t stream) {
    const float* x   = (const float*)d_in[0];
    // d_in[1] = batch (int64) — unused by the computation
    const float* W1  = (const float*)d_in[2];
    const float* b1  = (const float*)d_in[3];
    const float* g1  = (const float*)d_in[4];
    const float* be1 = (const float*)d_in[5];
    const float* Wa  = (const float*)d_in[6];
    const float* ba  = (const float*)d_in[7];
    const float* ga  = (const float*)d_in[8];
    const float* bea = (const float*)d_in[9];
    const float* Wb  = (const float*)d_in[10];
    const float* bb  = (const float*)d_in[11];
    const float* gb  = (const float*)d_in[12];
    const float* beb = (const float*)d_in[13];
    const float* Wc  = (const float*)d_in[14];
    const float* bc  = (const float*)d_in[15];
    float* out = (float*)d_out;
    float* acc = (float*)d_ws;      // [B,448] accumulator

    hipMemsetAsync(acc, 0, (size_t)BB * 448 * sizeof(float), stream);

    dim3 grid(16, BB, 7);
    knn_edge_kernel<<<grid, 256, 0, stream>>>(x, W1, b1, g1, be1, acc);
    head_kernel<<<BB, 512, 0, stream>>>(acc, Wa, ba, ga, bea,
                                        Wb, bb, gb, beb, Wc, bc, out);
}